// Round 1
// baseline (89.094 us; speedup 1.0000x reference)
//
#include <hip/hip_runtime.h>

#define SP 56
#define CH 64
#define XSTRIDE 3136   // 56*56 = per-j stride in x, per-i stride in out

// ---------------------------------------------------------------------------
// Prep: build combined coefficient tables from W (64,3,2,64) = W[i][kt][l][j].
// For o>=1 the reference collapses to a 4-tap vertical correlation:
//   g=o-2: C0=W[i,0,1,j]; g=o-1: C1=W[i,0,0,j]+W[i,1,1,j];
//   g=o  : C2=W[i,1,0,j]+W[i,2,1,j]; g=o+1: C3=W[i,2,0,j]
// o==0 wraps (o-1 -> 55): taps rows {0,1,54,55} with
//   D = {W[i,1,0,j], W[i,2,0,j], W[i,0,1,j], W[i,1,1,j]}
// Layout: Cv[j*64+i] = float4(C0..C3); D table at float4 offset 4096.
// Lane mapping (j = u&63, i = u>>6): all six W loads coalesced 256B.
// ---------------------------------------------------------------------------
__global__ void tsc_prep(const float* __restrict__ W, float4* __restrict__ Cv) {
  int u = blockIdx.x * blockDim.x + threadIdx.x;
  if (u >= CH * CH) return;
  int j = u & 63;
  int i = u >> 6;
  const float* Wi = W + i * 384 + j;   // W[i][kt][l][j]: kt stride 128, l stride 64
  float w00 = Wi[0];
  float w01 = Wi[64];
  float w10 = Wi[128];
  float w11 = Wi[192];
  float w20 = Wi[256];
  float w21 = Wi[320];
  Cv[j * 64 + i]        = make_float4(w01, w00 + w11, w10 + w21, w20);
  Cv[4096 + j * 64 + i] = make_float4(w10, w20, w01, w11);
}

// ---------------------------------------------------------------------------
// Main (R6): block = (oq 0..13, n 0..55) -> 4 output rows o = 4*oq..4*oq+3,
// one column n. The SAME 8-row x window (g = o0-2 .. o0+5) that previously
// fed 2 rows feeds 4 rows (taps b0..b6), so staging cost per block is
// unchanged while block count halves (1568 -> 784, ~3.1/CU, 12 waves/CU).
// Coefficients c[16] are prefetched into registers BEFORE the barrier so the
// L3-cold Cv latency overlaps the HBM-cold x staging latency (18 independent
// loads in flight per thread). __launch_bounds__(256,4) caps VGPR at 128 to
// hold 4 blocks/CU.
// ---------------------------------------------------------------------------
__global__ __launch_bounds__(256, 4) void tsc_main(const float* __restrict__ x,
                                                   const float4* __restrict__ Cv,
                                                   float* __restrict__ out) {
  __shared__ __align__(16) float xs[CH][8];  // 2 KB: xs[j][b], g = o0-2+b
  __shared__ float red[4][4][64];            // 4 KB: red[wave][row][i]

  const int t  = threadIdx.x;
  const int i  = t & 63;            // output channel (lane)
  const int w  = t >> 6;            // wave id 0..3
  const int oq = blockIdx.x;        // 0..13 (o-quad)
  const int n  = blockIdx.y;        // 0..55
  const int o0 = oq * 4;
  const int ns = (n + SP - 1) % SP; // (n-1) mod 56

  // ---- stage x window into LDS (2 loads per thread, coalesced in b) ----
  const float* xrow = x + ns * SP;
#pragma unroll
  for (int k = 0; k < 2; ++k) {
    int u = t + k * 256;                      // 0..511
    int j = u >> 3;
    int b = u & 7;
    int g = o0 - 2 + b;
    if (g < 0) g += SP;                       // circular bottom (only oq==0)
    float v = (g < SP) ? xrow[j * XSTRIDE + g] : 0.f;  // zero-pad top
    xs[j][b] = v;
  }

  // ---- prefetch coefficients while the x loads are still in flight ----
  const int j0 = w * 16;
  const float4* cb = Cv + i;
  float4 c[16];
#pragma unroll
  for (int jj = 0; jj < 16; ++jj) c[jj] = cb[(j0 + jj) * 64];

  __syncthreads();

  // ---- per-wave partial sums over 16 j values, 4 output rows ----
  float a0 = 0.f, a1 = 0.f, a2 = 0.f, a3 = 0.f;

  if (oq != 0) {
    // generic: rows o0..o0+3 use taps b = r..r+3 (top-edge g>=56 staged zero)
#pragma unroll
    for (int jj = 0; jj < 16; ++jj) {
      int j = j0 + jj;
      const float4* xv = (const float4*)xs[j];
      float4 xA = xv[0];               // b0..b3
      float4 xB = xv[1];               // b4..b7
      float4 cc = c[jj];
      a0 += cc.x * xA.x + cc.y * xA.y + cc.z * xA.z + cc.w * xA.w;
      a1 += cc.x * xA.y + cc.y * xA.z + cc.z * xA.w + cc.w * xB.x;
      a2 += cc.x * xA.z + cc.y * xA.w + cc.z * xB.x + cc.w * xB.y;
      a3 += cc.x * xA.w + cc.y * xB.x + cc.z * xB.y + cc.w * xB.z;
    }
  } else {
    // oq==0: xs[j][0]=row54, xs[j][1]=row55 (wrapped), xs[j][2..7]=rows 0..5
    // row0 (o=0): D taps on g {0,1,54,55}; row1 (o=1): g=-1 tap dropped;
    // rows 2,3: generic.
#pragma unroll 4
    for (int jj = 0; jj < 16; ++jj) {
      int j = j0 + jj;
      const float4* xv = (const float4*)xs[j];
      float4 xA = xv[0];
      float4 xB = xv[1];
      float4 cc = c[jj];
      float4 d  = cb[4096 + j * 64];
      a0 += d.x * xA.z + d.y * xA.w + d.z * xA.x + d.w * xA.y;
      a1 += cc.y * xA.z + cc.z * xA.w + cc.w * xB.x;
      a2 += cc.x * xA.z + cc.y * xA.w + cc.z * xB.x + cc.w * xB.y;
      a3 += cc.x * xA.w + cc.y * xB.x + cc.z * xB.y + cc.w * xB.z;
    }
  }

  red[w][0][i] = a0;
  red[w][1][i] = a1;
  red[w][2][i] = a2;
  red[w][3][i] = a3;
  __syncthreads();

  // ---- cross-wave reduction + store: all 256 threads -> (s = t>>6, i = t&63)
  {
    int s  = t >> 6;
    int ii = t & 63;
    float v = red[0][s][ii] + red[1][s][ii] + red[2][s][ii] + red[3][s][ii];
    out[ii * XSTRIDE + (o0 + s) * SP + n] = v;
  }
}

extern "C" void kernel_launch(void* const* d_in, const int* in_sizes, int n_in,
                              void* d_out, int out_size, void* d_ws, size_t ws_size,
                              hipStream_t stream) {
  const float* x = (const float*)d_in[0];
  const float* W = (const float*)d_in[1];
  float* out = (float*)d_out;
  float4* Cv = (float4*)d_ws;   // 8192 float4 = 128 KB scratch

  tsc_prep<<<dim3(16), dim3(256), 0, stream>>>(W, Cv);
  tsc_main<<<dim3(14, 56), dim3(256), 0, stream>>>(x, Cv, out);
}

// Round 2
// 65.080 us; speedup vs baseline: 1.3690x; 1.3690x over previous
//
#include <hip/hip_runtime.h>

#define SP 56
#define CH 64
#define XSTRIDE 3136   // 56*56 = per-j stride in x, per-i stride in out

// ---------------------------------------------------------------------------
// Prep: build combined coefficient tables from W (64,3,2,64) = W[i][kt][l][j].
// For o>=1 the reference collapses to a 4-tap vertical correlation:
//   g=o-2: C0=W[i,0,1,j]; g=o-1: C1=W[i,0,0,j]+W[i,1,1,j];
//   g=o  : C2=W[i,1,0,j]+W[i,2,1,j]; g=o+1: C3=W[i,2,0,j]
// o==0 wraps (o-1 -> 55): taps rows {0,1,54,55} with
//   D = {W[i,1,0,j], W[i,2,0,j], W[i,0,1,j], W[i,1,1,j]}
// Layout: Cv[j*64+i] = float4(C0..C3); D table at float4 offset 4096.
// Lane mapping (j = u&63, i = u>>6): all six W loads coalesced 256B.
// ---------------------------------------------------------------------------
__global__ void tsc_prep(const float* __restrict__ W, float4* __restrict__ Cv) {
  int u = blockIdx.x * blockDim.x + threadIdx.x;
  if (u >= CH * CH) return;
  int j = u & 63;
  int i = u >> 6;
  const float* Wi = W + i * 384 + j;   // W[i][kt][l][j]: kt stride 128, l stride 64
  float w00 = Wi[0];
  float w01 = Wi[64];
  float w10 = Wi[128];
  float w11 = Wi[192];
  float w20 = Wi[256];
  float w21 = Wi[320];
  Cv[j * 64 + i]        = make_float4(w01, w00 + w11, w10 + w21, w20);
  Cv[4096 + j * 64 + i] = make_float4(w10, w20, w01, w11);
}

// ---------------------------------------------------------------------------
// Main (R7): block = (o 0..55, n 0..55) -> ONE output row, one column.
// 3136 blocks x 128 threads (2 waves): 12.25 blocks/CU, ~24 waves/CU, up to
// 16 co-resident blocks. R6 post-mortem: kernel is latency-bound and block
// concurrency IS the latency hiding -- halving blocks (R6) cost 1.6x; this
// doubles them vs R5 instead. Per-block: stage 4-row x window (1KB LDS),
// wave w covers j in [32w,32w+32), lane = output channel i. 8 coefficient
// float4s (32 VGPR, not R6's spill-prone 64) prefetched before the barrier
// so their cold-cache latency folds into the barrier's vmcnt drain.
// 4 independent accumulator chains for FMA ILP.
// ---------------------------------------------------------------------------
__global__ __launch_bounds__(128) void tsc_main(const float* __restrict__ x,
                                                const float4* __restrict__ Cv,
                                                float* __restrict__ out) {
  __shared__ __align__(16) float xs[CH][4];  // 1 KB: xs[j][b], g = o-2+b
  __shared__ float red[64];                  // wave-1 partials

  const int t = threadIdx.x;
  const int i = t & 63;             // output channel (lane)
  const int w = t >> 6;             // wave id 0..1
  const int o = blockIdx.x;         // output row 0..55
  const int n = blockIdx.y;         // output col 0..55
  const int ns = (n + SP - 1) % SP; // (n-1) mod 56

  // ---- stage 4-row x window into LDS (2 loads per thread) ----
  const float* xrow = x + ns * SP;
#pragma unroll
  for (int k = 0; k < 2; ++k) {
    int u = t + k * 128;                     // 0..255
    int j = u >> 2;
    int b = u & 3;
    int g = o - 2 + b;
    if (g < 0) g += SP;                      // circular bottom (o==0,1 only)
    xs[j][b] = (g < SP) ? xrow[j * XSTRIDE + g] : 0.f;  // zero-pad top (o==55)
  }

  // ---- prefetch first 8 coefficient vectors while x loads are in flight ----
  const int j0 = w * 32;
  const float4* cb = Cv + i;
  float4 p0 = cb[(j0 + 0) * 64];
  float4 p1 = cb[(j0 + 1) * 64];
  float4 p2 = cb[(j0 + 2) * 64];
  float4 p3 = cb[(j0 + 3) * 64];
  float4 p4 = cb[(j0 + 4) * 64];
  float4 p5 = cb[(j0 + 5) * 64];
  float4 p6 = cb[(j0 + 6) * 64];
  float4 p7 = cb[(j0 + 7) * 64];

  __syncthreads();

  float a0 = 0.f, a1 = 0.f, a2 = 0.f, a3 = 0.f;

#define GSTEP(cc, jv) { const float4 xv = *(const float4*)(xs[jv]);            \
    a0 += (cc).x * xv.x; a1 += (cc).y * xv.y;                                  \
    a2 += (cc).z * xv.z; a3 += (cc).w * xv.w; }

  if (o >= 2) {
    // generic: taps g = o-2..o+1 at b = 0..3 (o==55: b3 staged zero)
    GSTEP(p0, j0 + 0) GSTEP(p1, j0 + 1) GSTEP(p2, j0 + 2) GSTEP(p3, j0 + 3)
    GSTEP(p4, j0 + 4) GSTEP(p5, j0 + 5) GSTEP(p6, j0 + 6) GSTEP(p7, j0 + 7)
#pragma unroll 8
    for (int jj = 8; jj < 32; ++jj) {
      const float4 cc = cb[(j0 + jj) * 64];
      GSTEP(cc, j0 + jj)
    }
  } else if (o == 1) {
    // xs[b] = rows {55, 0, 1, 2}; g=-1 tap dropped: C1..C3 on rows 0,1,2
#pragma unroll 8
    for (int jj = 0; jj < 32; ++jj) {
      const float4 cc = cb[(j0 + jj) * 64];
      const float4 xv = *(const float4*)(xs[j0 + jj]);
      a1 += cc.y * xv.y; a2 += cc.z * xv.z; a3 += cc.w * xv.w;
    }
  } else {
    // o==0: xs[b] = rows {54, 55, 0, 1}; D taps on g {0,1,54,55}
#pragma unroll 8
    for (int jj = 0; jj < 32; ++jj) {
      const float4 d = cb[4096 + (j0 + jj) * 64];
      const float4 xv = *(const float4*)(xs[j0 + jj]);
      a0 += d.x * xv.z; a1 += d.y * xv.w; a2 += d.z * xv.x; a3 += d.w * xv.y;
    }
  }
#undef GSTEP

  const float v = a0 + a1 + a2 + a3;

  // ---- cross-wave reduction + store ----
  if (w == 1) red[i] = v;
  __syncthreads();
  if (w == 0) out[i * XSTRIDE + o * SP + n] = v + red[i];
}

extern "C" void kernel_launch(void* const* d_in, const int* in_sizes, int n_in,
                              void* d_out, int out_size, void* d_ws, size_t ws_size,
                              hipStream_t stream) {
  const float* x = (const float*)d_in[0];
  const float* W = (const float*)d_in[1];
  float* out = (float*)d_out;
  float4* Cv = (float4*)d_ws;   // 8192 float4 = 128 KB scratch

  tsc_prep<<<dim3(16), dim3(256), 0, stream>>>(W, Cv);
  tsc_main<<<dim3(56, 56), dim3(128), 0, stream>>>(x, Cv, out);
}

// Round 3
// 62.393 us; speedup vs baseline: 1.4279x; 1.0431x over previous
//
#include <hip/hip_runtime.h>

#define SP 56
#define CH 64
#define XSTRIDE 3136   // 56*56 = per-j stride in x, per-i stride in out

// ---------------------------------------------------------------------------
// R8: single FUSED kernel (no prep launch, no workspace).
// Math (derived from ref, verified vs R5 tables):
//   out[i,o,n] = sum_j { C0*x[j,nn,o-2] + C1*x[j,nn,o-1] + C2*x[j,nn,o] + C3*x[j,nn,o+1] }
//   C = (w01, w00+w11, w10+w21, w20), w_kl = W[i,kt=k,l,j], nn=(n-1)%56,
//   rows g outside [0,56) are ZERO (pad), EXCEPT the o=0 row which wraps:
//   o==0: w01*x54 + w11*x55 + w10*x0 + w20*x1 ; o==1: C1*x0 + C2*x1 + C3*x2.
// Geometry: block = (4 o-rows, 1 col n, 32-channel half h). grid 14x56x2 =
// 1568 blocks x 4 waves = 6272 waves (R5's proven TLP). Lane l: il=l&31
// (channel within half), jh=l>>5; wave w covers j in {16w+8jh .. +8}.
// Phase 1: coalesced (lane=j) stream of the block's 48KB W slice -> C table
// in LDS Cw[64][33] float4 (+1 row pad -> bank-minimal both phases), plus
// 8-row x window. Phase 2: R5 FMA structure reading C from LDS.
// LDS 37.8 KB -> 4 blocks/CU capacity; launch_bounds(256,4) caps VGPR 128.
// ---------------------------------------------------------------------------
__global__ __launch_bounds__(256, 4) void tsc_fused(const float* __restrict__ x,
                                                    const float* __restrict__ W,
                                                    float* __restrict__ out) {
  __shared__ __align__(16) float4 Cw[CH][33];   // 33.8 KB, padded rows
  __shared__ __align__(16) float  xs[CH][8];    // 2 KB: xs[j][b], g = o0-2+b
  __shared__ float red[4][4][32];               // 2 KB: red[wave][r][il]

  const int t  = threadIdx.x;
  const int ob = blockIdx.x;        // 0..13 (o-quad)
  const int n  = blockIdx.y;        // 0..55
  const int h  = blockIdx.z;        // 0..1  (channel half)
  const int o0 = ob * 4;
  const int ns = (n + SP - 1) % SP; // (n-1) mod 56

  // ---- phase 1a: W slice -> LDS coefficient table (lane = j, coalesced) ----
  {
    const int j  = t & 63;
    const int ig = t >> 6;          // 0..3 -> il = ig*8 + q
#pragma unroll
    for (int q = 0; q < 8; ++q) {
      const int il = ig * 8 + q;
      const float* Wp = W + (h * 32 + il) * 384 + j;  // W[i][kt][l][j]
      float w00 = Wp[0],   w01 = Wp[64],  w10 = Wp[128];
      float w11 = Wp[192], w20 = Wp[256], w21 = Wp[320];
      Cw[j][il] = make_float4(w01, w00 + w11, w10 + w21, w20);
    }
  }

  // ---- phase 1b: stage 8-row x window (same pattern as R5) ----
  {
    const float* xrow = x + ns * SP;
#pragma unroll
    for (int k = 0; k < 2; ++k) {
      int u = t + k * 256;                    // 0..511
      int j = u >> 3;
      int b = u & 7;
      int g = o0 - 2 + b;
      if (g < 0) g += SP;                     // circular bottom (ob==0 only)
      xs[j][b] = (g < SP) ? xrow[j * XSTRIDE + g] : 0.f;  // zero-pad top
    }
  }
  __syncthreads();

  // ---- phase 2: per-thread partial sums, 8 j values, 4 output rows ----
  const int il = t & 31;
  const int jh = (t >> 5) & 1;
  const int w  = t >> 6;
  const int jbase = w * 16 + jh * 8;

  float a0 = 0.f, a1 = 0.f, a2 = 0.f, a3 = 0.f;

  if (ob != 0) {
#pragma unroll
    for (int jj = 0; jj < 8; ++jj) {
      const int j = jbase + jj;
      const float4 c  = Cw[j][il];
      const float4 xA = *(const float4*)&xs[j][0];
      const float4 xB = *(const float4*)&xs[j][4];
      a0 += c.x * xA.x + c.y * xA.y + c.z * xA.z + c.w * xA.w;
      a1 += c.x * xA.y + c.y * xA.z + c.z * xA.w + c.w * xB.x;
      a2 += c.x * xA.z + c.y * xA.w + c.z * xB.x + c.w * xB.y;
      a3 += c.x * xA.w + c.y * xB.x + c.z * xB.y + c.w * xB.z;
    }
  } else {
    // ob==0: xs[j][0]=row54, xs[j][1]=row55 (wrapped), xs[j][2..7]=rows 0..5
    // o=0: w01*x54 + w11*x55 + w10*x0 + w20*x1 ; o=1: C1..C3 on rows 0,1,2.
    const float* Wg = W + (h * 32 + il) * 384;  // L2-hot gather of w10,w11
#pragma unroll
    for (int jj = 0; jj < 8; ++jj) {
      const int j = jbase + jj;
      const float w10 = Wg[128 + j];
      const float w11 = Wg[192 + j];
      const float4 c  = Cw[j][il];
      const float4 xA = *(const float4*)&xs[j][0];
      const float4 xB = *(const float4*)&xs[j][4];
      a0 += c.x * xA.x + w11 * xA.y + w10 * xA.z + c.w * xA.w;
      a1 +=              c.y * xA.z + c.z * xA.w + c.w * xB.x;
      a2 += c.x * xA.z + c.y * xA.w + c.z * xB.x + c.w * xB.y;
      a3 += c.x * xA.w + c.y * xB.x + c.z * xB.y + c.w * xB.z;
    }
  }

  // ---- fold the two j-halves within each wave (lanes 0..31 <- +32) ----
  a0 += __shfl_down(a0, 32);
  a1 += __shfl_down(a1, 32);
  a2 += __shfl_down(a2, 32);
  a3 += __shfl_down(a3, 32);

  if ((t & 63) < 32) {
    red[w][0][il] = a0;
    red[w][1][il] = a1;
    red[w][2][il] = a2;
    red[w][3][il] = a3;
  }
  __syncthreads();

  // ---- cross-wave reduction + store: threads 0..127 -> (r = t>>5, il = t&31)
  if (t < 128) {
    const int r  = t >> 5;
    const int ii = t & 31;
    const float v = red[0][r][ii] + red[1][r][ii] + red[2][r][ii] + red[3][r][ii];
    out[(h * 32 + ii) * XSTRIDE + (o0 + r) * SP + n] = v;
  }
}

extern "C" void kernel_launch(void* const* d_in, const int* in_sizes, int n_in,
                              void* d_out, int out_size, void* d_ws, size_t ws_size,
                              hipStream_t stream) {
  const float* x = (const float*)d_in[0];
  const float* W = (const float*)d_in[1];
  float* out = (float*)d_out;
  (void)d_ws; (void)ws_size;   // workspace intentionally unused (no prep pass)

  tsc_fused<<<dim3(14, 56, 2), dim3(256), 0, stream>>>(x, W, out);
}